// Round 12
// baseline (26.161 us; speedup 1.0000x reference)
//
#include <hip/hip_runtime.h>
#include <hip/hip_fp16.h>

#define SR   9
#define SD   19
#define TW   16                 // tile width (pixels)
#define TH   6                  // tile height (pixels)
#define LW   (TW + 2*SR)        // 34 staged cols
#define LH   (TH + 2*SR)        // 24 staged rows
#define LS   42                 // LDS row stride; odd mod-32 spread
#define IMG  192
#define NPIX (IMG*IMG)

typedef __fp16 h2 __attribute__((ext_vector_type(2)));

// Block = 384 threads = 6 waves: 48 pixel-pair slots (8 pair-cols x 6 rows)
// x 8 dy-groups. Grid 12x32x2 = 768 blocks = exactly 3/CU.
//
// Inner loop in packed fp16 (VOP3P v_pk_*): halves = (pixel A, pixel B).
// Range kernel = cubic p(t), t=(c-n)^2, coefficients shifted per pixel by
// k=c^2 so t' = n^2-2cn suffices:  p = ((a3 t' + c2')t' + c1')t' + c0'.
// clamp(p,0,1) then scale by cx<=1: w = cx*clamp(p,0,1) == clamp(cx*p,0,1).
// 9 packed ops per dx covering both pixels ~= 4.5 VALU/px-tap (vs 7 scalar).
__global__ __launch_bounds__(384) void ms_iter(const float* __restrict__ in,
                                               float* __restrict__ out) {
    __shared__ __align__(16) float tile[LH * LS];
    __shared__ float4 part[8][48];

    const int b   = blockIdx.z;
    const int bx0 = blockIdx.x * TW;
    const int by0 = blockIdx.y * TH;
    const float* __restrict__ img = in + b * NPIX;

    const int tid = threadIdx.x;      // 0..383
    const int tz  = tid / 48;         // 0..7   dy group
    const int s   = tid - 48 * tz;    // 0..47  pixel-pair slot
    const int tx  = s & 7;            // pair col
    const int ty  = s >> 3;           // pixel row 0..5

    // stage padded tile (replication pad via clamp)
    for (int i = tid; i < LH * LW; i += 384) {
        int r  = i / LW, c = i - r * LW;
        int gy = min(max(by0 + r - SR, 0), IMG - 1);
        int gx = min(max(bx0 + c - SR, 0), IMG - 1);
        tile[r * LS + c] = img[gy * IMG + gx];
    }
    __syncthreads();

    // spatial-x factor exp(-(dx-9)^2/144) as broadcast half2 (VOP3P takes no
    // literals, so these become SGPR-resident constants)
    constexpr float CXf[SD] = {
        0.5697829f, 0.6411806f, 0.7115726f, 0.7788008f, 0.8406238f,
        0.8948393f, 0.9394131f, 0.9726045f, 0.9930797f, 1.0000000f,
        0.9930797f, 0.9726045f, 0.9394131f, 0.8948393f, 0.8406238f,
        0.7788008f, 0.7115726f, 0.6411806f, 0.5697829f
    };
    const float a3 = -0.8285240f;   // cubic for A*exp(-2t)-B

    const int   x0 = 2 * tx;
    const float cA = tile[(ty + SR) * LS + x0 + SR];
    const float cB = tile[(ty + SR) * LS + x0 + SR + 1];

    // per-pixel shifted coefficients (k = c^2) in f32, then packed (A,B)
    const float kA = cA * cA, kB = cB * cB;
    const float c2A = kA * -2.4855720f + 1.5534825f;
    const float c2B = kB * -2.4855720f + 1.5534825f;
    const float c1A = (kA * -2.4855720f + 3.1069650f) * kA + -1.5923197f;
    const float c1B = (kB * -2.4855720f + 3.1069650f) * kB + -1.5923197f;
    const float c0A = ((kA * a3 + 1.5534825f) * kA + -1.5923197f) * kA + 0.3138366f;
    const float c0B = ((kB * a3 + 1.5534825f) * kB + -1.5923197f) * kB + 0.3138366f;

    const h2 m2c2 = __builtin_amdgcn_cvt_pkrtz(-2.f * cA, -2.f * cB);
    const h2 c2_2 = __builtin_amdgcn_cvt_pkrtz(c2A, c2B);
    const h2 c1_2 = __builtin_amdgcn_cvt_pkrtz(c1A, c1B);
    const h2 c0_2 = __builtin_amdgcn_cvt_pkrtz(c0A, c0B);
    const h2 a3_2 = { (__fp16)(-0.8285240f), (__fp16)(-0.8285240f) };

    // dy rows per tz: {3,3,3,2,2,2,2,2}; only wave 2 mixes 3|2
    const int beg = (tz < 3) ? 3 * tz : (9 + 2 * (tz - 3));
    const int nr  = (tz < 3) ? 3 : 2;

    float numA = 0.f, denA = 0.f, numB = 0.f, denB = 0.f;
    for (int r = 0; r < nr; ++r) {
        const int   dy = beg + r;
        const float ft = (float)(dy - SR);
        const float fy = __builtin_amdgcn_exp2f(ft * ft * -0.010018715f);

        const float2* r2 = reinterpret_cast<const float2*>(&tile[(ty + dy) * LS + x0]);
        // even pairs hp[j]=(w2j,w2j+1); odd pairs via alignbit op[j]=(w2j+1,w2j+2)
        h2 hp[10];
#pragma unroll
        for (int j = 0; j < 10; ++j) {
            float2 v = r2[j];
            hp[j] = __builtin_amdgcn_cvt_pkrtz(v.x, v.y);
        }
        h2 op[9];
#pragma unroll
        for (int j = 0; j < 9; ++j) {
            unsigned lo = __builtin_bit_cast(unsigned, hp[j]);
            unsigned hi = __builtin_bit_cast(unsigned, hp[j + 1]);
            op[j] = __builtin_bit_cast(h2, __builtin_amdgcn_alignbit(hi, lo, 16));
        }

        h2 rn2 = { (__fp16)0.f, (__fp16)0.f };
        h2 rd2 = rn2;
#pragma unroll
        for (int dx = 0; dx < SD; ++dx) {
            h2 n  = (dx & 1) ? op[dx >> 1] : hp[dx >> 1];
            h2 cx = { (__fp16)CXf[dx], (__fp16)CXf[dx] };
            h2 h  = n * n;                         // pk_mul
            h2 t  = m2c2 * n + h;                  // pk_fma: t' = n^2 - 2cn
            h2 u  = a3_2 * t + c2_2;               // pk_fma
            u     = u * t + c1_2;                  // pk_fma
            u     = u * t + c0_2;                  // pk_fma
            h2 zero = { (__fp16)0.f, (__fp16)0.f };
            h2 one  = { (__fp16)1.f, (__fp16)1.f };
            u = __builtin_elementwise_min(__builtin_elementwise_max(u, zero), one);
            h2 w  = u * cx;                        // pk_mul (sgpr const)
            rn2   = w * n + rn2;                   // pk_fma
            rd2   = rd2 + w;                       // pk_add
        }
        numA += fy * (float)rn2[0];  numB += fy * (float)rn2[1];
        denA += fy * (float)rd2[0];  denB += fy * (float)rd2[1];
    }

    part[tz][s] = make_float4(numA, denA, numB, denB);
    __syncthreads();

    // final combine: 48 threads, one pixel-pair each
    if (tid < 48) {
        float nA = 0.f, dA = 0.f, nB = 0.f, dB = 0.f;
#pragma unroll
        for (int g = 0; g < 8; ++g) {
            float4 v = part[g][tid];
            nA += v.x; dA += v.y; nB += v.z; dB += v.w;
        }
        const float K = 0.04701581f;   // spatial amplitude 1/(SSIGMA*sqrt(2pi))
        float2 o;
        o.x = (K * nA) / (K * dA + 1e-8f);
        o.y = (K * nB) / (K * dB + 1e-8f);
        const int otx = tid & 7, oty = tid >> 3;
        *reinterpret_cast<float2*>(&out[b * NPIX + (by0 + oty) * IMG + bx0 + 2 * otx]) = o;
    }
}

extern "C" void kernel_launch(void* const* d_in, const int* in_sizes, int n_in,
                              void* d_out, int out_size, void* d_ws, size_t ws_size,
                              hipStream_t stream) {
    const float* in  = (const float*)d_in[0];
    float*       out = (float*)d_out;
    float*       ws  = (float*)d_ws;   // needs 2*192*192*4 = 294912 bytes

    dim3 grid(IMG / TW, IMG / TH, 2);   // 12 x 32 x 2 = 768 blocks = 3/CU exact
    dim3 block(384, 1, 1);              // 6 waves

    ms_iter<<<grid, block, 0, stream>>>(in, out);   // iter 1
    ms_iter<<<grid, block, 0, stream>>>(out, ws);   // iter 2
    ms_iter<<<grid, block, 0, stream>>>(ws, out);   // iter 3
}